// Round 8
// baseline (90.133 us; speedup 1.0000x reference)
//
#include <hip/hip_runtime.h>
#include <hip/hip_bf16.h>

#define NB 8
#define NU 8192
#define GN0 64
#define GN1 64
#define NS 4096
#define NE 128
#define NH 8
#define CAP 20
#define NPTS (NB * NU)               // 65536
#define NCELL (NB * NS)              // 32768
#define OUT0 (NB * GN0 * GN1 * 2)    // 65536 f32 passthrough

// ---------------------------------------------------------------------------
// ws layout (bytes), total ~27.8 MB:
//   counts @ 0        (131072)   int32 per cell (zeroed by setup_kernel)
//   lists  @ 131072   (1310720)  u16 point ids per cell
//   S      @ 1441792  (2097152)  f32 scores [NPTS][8] (pre-scaled by 0.25)
//   G      @ 3538944  (8388608)  bf16 [NS][8][128]: Wk_h @ q_{s,h}
//   FS     @ 11927552 (131072)   f32 [NS][8] fake-token scores (pre-scaled)
//   fakeKV @ 12058624 (1024)     f32 fakeK[128], fakeV[128]
//   Wvt    @ 12059648 (32768)    bf16 Wv^T [col][k]
//   Wot    @ 12092416 (32768)    bf16 Wo^T [col][k]
//   Vb     @ 12125184 (16777216) bf16 V = Z @ Wv
//   ps     @ 28902400 (131072)   u16 per-point s-index
// ---------------------------------------------------------------------------

typedef __attribute__((ext_vector_type(8))) short short8v;
typedef __attribute__((ext_vector_type(4))) float float4v;

static __device__ inline unsigned pk2(float a, float b) {
  __hip_bfloat16 x = __float2bfloat16(a), y = __float2bfloat16(b);
  return ((unsigned)*(unsigned short*)&y << 16) | *(unsigned short*)&x;
}
static __device__ inline float bfs(short v) {
  unsigned u = (unsigned)(unsigned short)v << 16;
  return __builtin_bit_cast(float, u);
}

// fused: out0 passthrough + counts zero + fakeKV row + Wv^T/Wo^T bf16 staging
__global__ __launch_bounds__(256) void setup_kernel(
    const float* __restrict__ xc_on, const float* __restrict__ fake,
    const float* __restrict__ Wk, const float* __restrict__ Wv,
    const float* __restrict__ Wo,
    float* __restrict__ out, int* __restrict__ counts,
    float* __restrict__ fakeKV, __hip_bfloat16* __restrict__ Wvt,
    __hip_bfloat16* __restrict__ Wot) {
  int t = threadIdx.x;
  int i = blockIdx.x * 256 + t;
  out[i] = xc_on[i];                 // grid = OUT0/256, exact
  if (i < NCELL) counts[i] = 0;
  if (blockIdx.x == 0) {
    __shared__ float frow[NE];
    if (t < NE) frow[t] = fake[t];
    __syncthreads();
    int e = t & 127, half = t >> 7;
    const float* W = half ? Wv : Wk;
    float acc = 0.f;
    for (int j = 0; j < NE; ++j) acc += frow[j] * W[j * NE + e];
    fakeKV[half * NE + e] = acc;
  } else if (blockIdx.x <= 64) {
    int flat = (blockIdx.x - 1) * 256 + t;   // 0..16383
    int j = flat >> 7, e = flat & 127;
    Wvt[e * NE + j] = __float2bfloat16(Wv[flat]);
    Wot[e * NE + j] = __float2bfloat16(Wo[flat]);
  }
}

__global__ __launch_bounds__(256) void nearest_kernel(
    const float* __restrict__ xc_off, const float* __restrict__ xc_on,
    int* __restrict__ counts, unsigned short* __restrict__ lists,
    unsigned short* __restrict__ ps) {
  int idx = blockIdx.x * blockDim.x + threadIdx.x;
  if (idx >= NPTS) return;
  int b = idx >> 13;
  const float* g = xc_on + (size_t)b * (GN0 * GN1 * 2);
  float c00 = g[0], c01 = g[GN1 * 2], c10 = g[1], c11 = g[3];
  float x0 = xc_off[(size_t)idx * 2 + 0];
  float x1 = xc_off[(size_t)idx * 2 + 1];
  float f0 = rintf((x0 - c00) / (c01 - c00));   // np.round = RNE
  float f1 = rintf((x1 - c10) / (c11 - c10));
  int i0 = (int)fminf(fmaxf(f0, 0.f), 63.f);
  int i1 = (int)fminf(fmaxf(f1, 0.f), 63.f);
  int s = i0 * GN1 + i1;
  ps[idx] = (unsigned short)s;
  int cell = b * NS + s;
  int pos = atomicAdd(&counts[cell], 1);
  if (pos < CAP) lists[cell * CAP + pos] = (unsigned short)idx;
}

// per 8 latent rows: q = latent @ Wq (kept in LDS), then G[s][h][:] and FS
__global__ __launch_bounds__(256) void prep_kernel(
    const float* __restrict__ latents, const float* __restrict__ Wq,
    const float* __restrict__ Wk, const float* __restrict__ fakeKV,
    __hip_bfloat16* __restrict__ G, float* __restrict__ FS) {
  int s0 = blockIdx.x * 8;
  int tid = threadIdx.x;
  __shared__ float lrow[8][NE];
  __shared__ float qs[8][NE];
  for (int i = tid; i < 8 * NE; i += 256)
    lrow[i >> 7][i & 127] = latents[(size_t)s0 * NE + i];
  __syncthreads();
  for (int i = tid; i < 8 * NE; i += 256) {
    int sl = i >> 7, e = i & 127;
    float acc = 0.f;
    for (int j = 0; j < NE; ++j) acc += lrow[sl][j] * Wq[j * NE + e];
    qs[sl][e] = acc;
  }
  __syncthreads();
  int j = tid & 127, half = tid >> 7;
  for (int hh = 0; hh < 4; ++hh) {
    int h = half * 4 + hh;
    float wkr[16];
#pragma unroll
    for (int d = 0; d < 16; ++d) wkr[d] = Wk[j * NE + h * 16 + d];
    for (int sl = 0; sl < 8; ++sl) {
      float acc = 0.f;
#pragma unroll
      for (int d = 0; d < 16; ++d) acc += wkr[d] * qs[sl][h * 16 + d];
      G[((size_t)(s0 + sl) * 8 + h) * NE + j] = __float2bfloat16(acc);
    }
  }
  if (tid < 64) {
    int sl = tid >> 3, h = tid & 7;
    float acc = 0.f;
#pragma unroll
    for (int d = 0; d < 16; ++d) acc += qs[sl][h * 16 + d] * fakeKV[h * 16 + d];
    FS[(size_t)(s0 + sl) * 8 + h] = acc * 0.25f;
  }
}

// fused: V = bf16(Z @ Wv) via MFMA  +  per-point scores from the LDS z tile.
// 64 points/block, 256 threads (4 waves).
__global__ __launch_bounds__(256) void vgemm_scores_kernel(
    const float* __restrict__ z, const unsigned short* __restrict__ ps,
    const __hip_bfloat16* __restrict__ Wvt, const __hip_bfloat16* __restrict__ G,
    __hip_bfloat16* __restrict__ Vb, float* __restrict__ S) {
  __shared__ __hip_bfloat16 zb[64 * 136];
  __shared__ __hip_bfloat16 wv[128 * 136];
  int tid = threadIdx.x;
  size_t row0 = (size_t)blockIdx.x * 64;
  for (int n = 0; n < 8; ++n) {
    int flat = n * 1024 + tid * 4;       // 0..8191 f32
    int r = flat >> 7, c = flat & 127;
    float4 v = *(const float4*)&z[(row0 + r) * NE + c];
    uint2 u = {pk2(v.x, v.y), pk2(v.z, v.w)};
    *(uint2*)&zb[r * 136 + c] = u;
  }
  const short* Wg = (const short*)Wvt;
  short* wl = (short*)wv;
  for (int n = 0; n < 8; ++n) {
    int chunk = n * 256 + tid;           // 0..2047 x 16B
    int r = chunk >> 4, c16 = chunk & 15;
    short8v v = *(const short8v*)&Wg[r * NE + c16 * 8];
    *(short8v*)&wl[r * 136 + c16 * 8] = v;
  }
  __syncthreads();
  int wid = tid >> 6, l = tid & 63;
  int lr = l & 15, lk = l >> 4;
  const short* zl = (const short*)zb;
  // --- V projection (MFMA) ---
  {
    float4v acc[4][2] = {};
    short8v bfrag[2][4];
#pragma unroll
    for (int ct = 0; ct < 2; ++ct) {
      int col = (wid * 2 + ct) * 16 + lr;
#pragma unroll
      for (int ks = 0; ks < 4; ++ks)
        bfrag[ct][ks] = *(const short8v*)&wl[col * 136 + ks * 32 + lk * 8];
    }
#pragma unroll
    for (int ks = 0; ks < 4; ++ks)
#pragma unroll
      for (int st = 0; st < 4; ++st) {
        short8v a = *(const short8v*)&zl[(st * 16 + lr) * 136 + ks * 32 + lk * 8];
        acc[st][0] = __builtin_amdgcn_mfma_f32_16x16x32_bf16(a, bfrag[0][ks], acc[st][0], 0, 0, 0);
        acc[st][1] = __builtin_amdgcn_mfma_f32_16x16x32_bf16(a, bfrag[1][ks], acc[st][1], 0, 0, 0);
      }
#pragma unroll
    for (int st = 0; st < 4; ++st)
#pragma unroll
      for (int ct = 0; ct < 2; ++ct)
#pragma unroll
        for (int r = 0; r < 4; ++r) {
          size_t row = row0 + st * 16 + lk * 4 + r;
          int col = (wid * 2 + ct) * 16 + lr;
          Vb[row * NE + col] = __float2bfloat16(acc[st][ct][r]);
        }
  }
  // --- scores: wave handles 16 points from the LDS z tile ---
#pragma unroll 2
  for (int i = 0; i < 16; ++i) {
    int lp = wid * 16 + i;               // local point row
    size_t p = row0 + lp;
    int s = ps[p];
    const short8v* g8 = (const short8v*)(G + (size_t)s * (8 * NE));
    short8v ga = g8[l];                  // head l>>4, d=(l&15)*8+j
    short8v gb = g8[64 + l];             // head 4+(l>>4)
    short8v zz = *(const short8v*)&zl[lp * 136 + (l & 15) * 8];
    float pa = 0.f, pb = 0.f;
#pragma unroll
    for (int j = 0; j < 8; ++j) {
      float zf = bfs(zz[j]);
      pa += zf * bfs(ga[j]);
      pb += zf * bfs(gb[j]);
    }
#pragma unroll
    for (int off = 1; off < 16; off <<= 1) {
      pa += __shfl_xor(pa, off);
      pb += __shfl_xor(pb, off);
    }
    if ((l & 15) == 0) {
      S[p * 8 + (l >> 4)] = pa * 0.25f;
      S[p * 8 + 4 + (l >> 4)] = pb * 0.25f;
    }
  }
}

// fused attention + Wo: 64 cells/block, 16 waves; per-cell phase is wave-local
// (sc[w]/pl[w] touched only by wave w; same-wave DS ops are in-order), so the
// only block barrier is the MFMA join.
__global__ __launch_bounds__(1024) void attn_wo_kernel(
    const __hip_bfloat16* __restrict__ Vb, const float* __restrict__ S,
    const float* __restrict__ FS, const float* __restrict__ fakeKV,
    const int* __restrict__ counts, const unsigned short* __restrict__ lists,
    const __hip_bfloat16* __restrict__ Wot, float* __restrict__ out) {
  __shared__ __hip_bfloat16 ob[64 * 136];   // O tile (bf16)
  __shared__ __hip_bfloat16 wo[128 * 136];  // Wo^T staged
  __shared__ float sc[16][24][8];
  __shared__ unsigned short pl[16][24];
  int tid = threadIdx.x, w = tid >> 6, l = tid & 63;
  {
    const short* Wg = (const short*)Wot;
    short* wl = (short*)wo;
#pragma unroll
    for (int n = 0; n < 2; ++n) {
      int chunk = n * 1024 + tid;
      int r = chunk >> 4, c16 = chunk & 15;
      *(short8v*)&wl[r * 136 + c16 * 8] = *(const short8v*)&Wg[r * NE + c16 * 8];
    }
  }
  int cell0 = blockIdx.x * 64;
  for (int ci = 0; ci < 4; ++ci) {
    int row = w * 4 + ci;
    int cell = cell0 + row;
    int s = cell & (NS - 1);
    int cnt = min(counts[cell], CAP);
    if (l < cnt) {
      int pid = lists[cell * CAP + l];
      pl[w][l] = (unsigned short)pid;
      float4 a = *(const float4*)&S[(size_t)pid * 8];
      float4 b = *(const float4*)&S[(size_t)pid * 8 + 4];
      sc[w][l][0] = a.x; sc[w][l][1] = a.y; sc[w][l][2] = a.z; sc[w][l][3] = a.w;
      sc[w][l][4] = b.x; sc[w][l][5] = b.y; sc[w][l][6] = b.z; sc[w][l][7] = b.w;
    } else if (l == cnt) {
#pragma unroll
      for (int h = 0; h < 8; ++h) sc[w][l][h] = FS[(size_t)s * 8 + h];
    }
    __builtin_amdgcn_wave_barrier();
    if (l < 8) {
      int T = cnt + 1;
      float m = -1e30f;
      for (int t = 0; t < T; ++t) m = fmaxf(m, sc[w][t][l]);
      float sum = 0.f;
      for (int t = 0; t < T; ++t) {
        float e = __expf(sc[w][t][l] - m);
        sum += e;
        sc[w][t][l] = e;
      }
      float inv = 1.f / sum;
      for (int t = 0; t < T; ++t) sc[w][t][l] *= inv;
    }
    __builtin_amdgcn_wave_barrier();
    // PV: lane l covers d = 2l, 2l+1 (head l>>3); one dword V load per token
    int h = l >> 3;
    float acc0 = 0.f, acc1 = 0.f;
    for (int t = 0; t < cnt; ++t) {
      unsigned vv = ((const unsigned*)(Vb + (size_t)pl[w][t] * NE))[l];
      float wt = sc[w][t][h];
      acc0 += wt * bfs((short)(vv & 0xffff));
      acc1 += wt * bfs((short)(vv >> 16));
    }
    float2 fv = *(const float2*)&fakeKV[NE + 2 * l];
    float wt = sc[w][cnt][h];
    acc0 += wt * fv.x;
    acc1 += wt * fv.y;
    *(unsigned*)&ob[row * 136 + 2 * l] = pk2(acc0, acc1);
  }
  __syncthreads();
  // Wo MFMA epilogue: 16 waves, wave = (row-pair, col-tile)
  int lr = l & 15, lk = l >> 4;
  int ct = w & 7;                 // col tile 0..7
  int st0 = (w >> 3) * 2;         // row strips {st0, st0+1}
  int col = ct * 16 + lr;
  const short* ol = (const short*)ob;
  const short* wl = (const short*)wo;
  float4v acc[2] = {};
  short8v bfrag[4];
#pragma unroll
  for (int ks = 0; ks < 4; ++ks)
    bfrag[ks] = *(const short8v*)&wl[col * 136 + ks * 32 + lk * 8];
#pragma unroll
  for (int ks = 0; ks < 4; ++ks)
#pragma unroll
    for (int i = 0; i < 2; ++i) {
      short8v a = *(const short8v*)&ol[((st0 + i) * 16 + lr) * 136 + ks * 32 + lk * 8];
      acc[i] = __builtin_amdgcn_mfma_f32_16x16x32_bf16(a, bfrag[ks], acc[i], 0, 0, 0);
    }
  float* base = out + (size_t)OUT0 + (size_t)blockIdx.x * 64 * NE;
#pragma unroll
  for (int i = 0; i < 2; ++i)
#pragma unroll
    for (int r = 0; r < 4; ++r) {
      int row = (st0 + i) * 16 + lk * 4 + r;
      base[(size_t)row * NE + col] = acc[i][r];
    }
}

extern "C" void kernel_launch(void* const* d_in, const int* in_sizes, int n_in,
                              void* d_out, int out_size, void* d_ws, size_t ws_size,
                              hipStream_t stream) {
  const float* xc_off  = (const float*)d_in[0];
  const float* xc_on   = (const float*)d_in[1];
  const float* zc_off  = (const float*)d_in[2];
  const float* latents = (const float*)d_in[4];
  const float* fake    = (const float*)d_in[5];
  const float* Wq      = (const float*)d_in[6];
  const float* Wk      = (const float*)d_in[7];
  const float* Wv      = (const float*)d_in[8];
  const float* Wo      = (const float*)d_in[9];
  float* out = (float*)d_out;

  char* ws = (char*)d_ws;
  int*            counts = (int*)(ws);
  unsigned short* lists  = (unsigned short*)(ws + 131072);
  float*          S      = (float*)(ws + 1441792);
  __hip_bfloat16* G      = (__hip_bfloat16*)(ws + 3538944);
  float*          FS     = (float*)(ws + 11927552);
  float*          fakeKV = (float*)(ws + 12058624);
  __hip_bfloat16* Wvt    = (__hip_bfloat16*)(ws + 12059648);
  __hip_bfloat16* Wot    = (__hip_bfloat16*)(ws + 12092416);
  __hip_bfloat16* Vb     = (__hip_bfloat16*)(ws + 12125184);
  unsigned short* ps     = (unsigned short*)(ws + 28902400);

  hipLaunchKernelGGL(setup_kernel, dim3(OUT0 / 256), dim3(256), 0, stream,
                     xc_on, fake, Wk, Wv, Wo, out, counts, fakeKV, Wvt, Wot);
  hipLaunchKernelGGL(nearest_kernel, dim3(NPTS / 256), dim3(256), 0, stream,
                     xc_off, xc_on, counts, lists, ps);
  hipLaunchKernelGGL(prep_kernel, dim3(NS / 8), dim3(256), 0, stream,
                     latents, Wq, Wk, fakeKV, G, FS);
  hipLaunchKernelGGL(vgemm_scores_kernel, dim3(NPTS / 64), dim3(256), 0, stream,
                     zc_off, ps, Wvt, G, Vb, S);
  hipLaunchKernelGGL(attn_wo_kernel, dim3(NCELL / 64), dim3(1024), 0, stream,
                     Vb, S, FS, fakeKV, counts, lists, Wot, out);
}

// Round 9
// 84.154 us; speedup vs baseline: 1.0711x; 1.0711x over previous
//
#include <hip/hip_runtime.h>
#include <hip/hip_bf16.h>

#define NB 8
#define NU 8192
#define GN0 64
#define GN1 64
#define NS 4096
#define NE 128
#define NH 8
#define CAP 20
#define NPTS (NB * NU)               // 65536
#define NCELL (NB * NS)              // 32768
#define OUT0 (NB * GN0 * GN1 * 2)    // 65536 f32 passthrough

// ---------------------------------------------------------------------------
// ws layout (bytes), total ~27.8 MB (ps buffer dropped):
//   counts @ 0        (131072)   int32 per cell (zeroed by setup blocks)
//   lists  @ 131072   (1310720)  u16 point ids per cell
//   S      @ 1441792  (2097152)  f32 scores [NPTS][8] (pre-scaled by 0.25)
//   G      @ 3538944  (8388608)  bf16 [NS][8][128]: Wk_h @ q_{s,h}
//   FS     @ 11927552 (131072)   f32 [NS][8] fake-token scores (pre-scaled)
//   fakeKV @ 12058624 (1024)     f32 fakeK[128], fakeV[128]
//   Wvt    @ 12059648 (32768)    bf16 Wv^T [col][k]
//   Wot    @ 12092416 (32768)    bf16 Wo^T [col][k]
//   Vb     @ 12125184 (16777216) bf16 V = Z @ Wv
// ---------------------------------------------------------------------------

typedef __attribute__((ext_vector_type(8))) short short8v;
typedef __attribute__((ext_vector_type(4))) float float4v;

static __device__ inline unsigned pk2(float a, float b) {
  __hip_bfloat16 x = __float2bfloat16(a), y = __float2bfloat16(b);
  return ((unsigned)*(unsigned short*)&y << 16) | *(unsigned short*)&x;
}
static __device__ inline float bfs(short v) {
  unsigned u = (unsigned)(unsigned short)v << 16;
  return __builtin_bit_cast(float, u);
}

// one kernel, block-range dispatch:
//   blocks 0..255   : out0 passthrough copy (+ counts zero on blocks 0..127)
//   block  256      : fakeKV row
//   blocks 257..320 : Wv^T / Wo^T bf16 staging
//   blocks 321..832 : prep (q = latents@Wq, G, FS)  [recomputes fakeK locally]
__global__ __launch_bounds__(256) void setup_prep_kernel(
    const float* __restrict__ xc_on, const float* __restrict__ fake,
    const float* __restrict__ latents,
    const float* __restrict__ Wq, const float* __restrict__ Wk,
    const float* __restrict__ Wv, const float* __restrict__ Wo,
    float* __restrict__ out, int* __restrict__ counts,
    float* __restrict__ fakeKV, __hip_bfloat16* __restrict__ Wvt,
    __hip_bfloat16* __restrict__ Wot,
    __hip_bfloat16* __restrict__ G, float* __restrict__ FS) {
  int t = threadIdx.x;
  int blk = blockIdx.x;
  if (blk < 256) {
    int i = blk * 256 + t;
    out[i] = xc_on[i];
    if (i < NCELL) counts[i] = 0;
    return;
  }
  if (blk == 256) {
    __shared__ float frow[NE];
    if (t < NE) frow[t] = fake[t];
    __syncthreads();
    int e = t & 127, half = t >> 7;
    const float* W = half ? Wv : Wk;
    float acc = 0.f;
    for (int j = 0; j < NE; ++j) acc += frow[j] * W[j * NE + e];
    fakeKV[half * NE + e] = acc;
    return;
  }
  if (blk <= 320) {
    int flat = (blk - 257) * 256 + t;    // 0..16383
    int j = flat >> 7, e = flat & 127;
    Wvt[e * NE + j] = __float2bfloat16(Wv[flat]);
    Wot[e * NE + j] = __float2bfloat16(Wo[flat]);
    return;
  }
  // ---- prep section: 512 blocks, 8 latent rows each ----
  int s0 = (blk - 321) * 8;
  __shared__ float lrow[8][NE];
  __shared__ float qs[8][NE];
  __shared__ float frow[NE];
  __shared__ float fk[NE];
  for (int i = t; i < 8 * NE; i += 256)
    lrow[i >> 7][i & 127] = latents[(size_t)s0 * NE + i];
  if (t < NE) frow[t] = fake[t];
  __syncthreads();
  for (int i = t; i < 8 * NE; i += 256) {
    int sl = i >> 7, e = i & 127;
    float acc = 0.f;
    for (int j = 0; j < NE; ++j) acc += lrow[sl][j] * Wq[j * NE + e];
    qs[sl][e] = acc;
  }
  if (t < NE) {
    float acc = 0.f;
    for (int j = 0; j < NE; ++j) acc += frow[j] * Wk[j * NE + t];
    fk[t] = acc;
  }
  __syncthreads();
  int j = t & 127, half = t >> 7;
  for (int hh = 0; hh < 4; ++hh) {
    int h = half * 4 + hh;
    float wkr[16];
#pragma unroll
    for (int d = 0; d < 16; ++d) wkr[d] = Wk[j * NE + h * 16 + d];
    for (int sl = 0; sl < 8; ++sl) {
      float acc = 0.f;
#pragma unroll
      for (int d = 0; d < 16; ++d) acc += wkr[d] * qs[sl][h * 16 + d];
      G[((size_t)(s0 + sl) * 8 + h) * NE + j] = __float2bfloat16(acc);
    }
  }
  if (t < 64) {
    int sl = t >> 3, h = t & 7;
    float acc = 0.f;
#pragma unroll
    for (int d = 0; d < 16; ++d) acc += qs[sl][h * 16 + d] * fk[h * 16 + d];
    FS[(size_t)(s0 + sl) * 8 + h] = acc * 0.25f;
  }
}

// fused: nearest-cell assignment (wave 0) + V = bf16(Z@Wv) MFMA + scores.
// 64 points/block (one batch per block since NU%64==0), 256 threads.
__global__ __launch_bounds__(256) void vgemm_kernel(
    const float* __restrict__ z, const float* __restrict__ xc_off,
    const float* __restrict__ xc_on,
    const __hip_bfloat16* __restrict__ Wvt, const __hip_bfloat16* __restrict__ G,
    int* __restrict__ counts, unsigned short* __restrict__ lists,
    __hip_bfloat16* __restrict__ Vb, float* __restrict__ S) {
  __shared__ __hip_bfloat16 zb[64 * 136];
  __shared__ __hip_bfloat16 wv[128 * 136];
  __shared__ unsigned short s_idx[64];
  int tid = threadIdx.x;
  size_t row0 = (size_t)blockIdx.x * 64;
  for (int n = 0; n < 8; ++n) {
    int flat = n * 1024 + tid * 4;       // 0..8191 f32
    int r = flat >> 7, c = flat & 127;
    float4 v = *(const float4*)&z[(row0 + r) * NE + c];
    uint2 u = {pk2(v.x, v.y), pk2(v.z, v.w)};
    *(uint2*)&zb[r * 136 + c] = u;
  }
  if (tid < 64) {                        // nearest: one lane per point
    int p = (int)row0 + tid;
    int b = p >> 13;
    const float* g = xc_on + (size_t)b * (GN0 * GN1 * 2);
    float c00 = g[0], c01 = g[GN1 * 2], c10 = g[1], c11 = g[3];
    float x0 = xc_off[(size_t)p * 2 + 0];
    float x1 = xc_off[(size_t)p * 2 + 1];
    float f0 = rintf((x0 - c00) / (c01 - c00));   // np.round = RNE
    float f1 = rintf((x1 - c10) / (c11 - c10));
    int i0 = (int)fminf(fmaxf(f0, 0.f), 63.f);
    int i1 = (int)fminf(fmaxf(f1, 0.f), 63.f);
    int s = i0 * GN1 + i1;
    s_idx[tid] = (unsigned short)s;
    int cell = b * NS + s;
    int pos = atomicAdd(&counts[cell], 1);
    if (pos < CAP) lists[cell * CAP + pos] = (unsigned short)p;
  }
  const short* Wg = (const short*)Wvt;
  short* wl = (short*)wv;
  for (int n = 0; n < 8; ++n) {
    int chunk = n * 256 + tid;           // 0..2047 x 16B
    int r = chunk >> 4, c16 = chunk & 15;
    short8v v = *(const short8v*)&Wg[r * NE + c16 * 8];
    *(short8v*)&wl[r * 136 + c16 * 8] = v;
  }
  __syncthreads();
  int wid = tid >> 6, l = tid & 63;
  int lr = l & 15, lk = l >> 4;
  const short* zl = (const short*)zb;
  // --- V projection (MFMA) ---
  {
    float4v acc[4][2] = {};
    short8v bfrag[2][4];
#pragma unroll
    for (int ct = 0; ct < 2; ++ct) {
      int col = (wid * 2 + ct) * 16 + lr;
#pragma unroll
      for (int ks = 0; ks < 4; ++ks)
        bfrag[ct][ks] = *(const short8v*)&wl[col * 136 + ks * 32 + lk * 8];
    }
#pragma unroll
    for (int ks = 0; ks < 4; ++ks)
#pragma unroll
      for (int st = 0; st < 4; ++st) {
        short8v a = *(const short8v*)&zl[(st * 16 + lr) * 136 + ks * 32 + lk * 8];
        acc[st][0] = __builtin_amdgcn_mfma_f32_16x16x32_bf16(a, bfrag[0][ks], acc[st][0], 0, 0, 0);
        acc[st][1] = __builtin_amdgcn_mfma_f32_16x16x32_bf16(a, bfrag[1][ks], acc[st][1], 0, 0, 0);
      }
#pragma unroll
    for (int st = 0; st < 4; ++st)
#pragma unroll
      for (int ct = 0; ct < 2; ++ct)
#pragma unroll
        for (int r = 0; r < 4; ++r) {
          size_t row = row0 + st * 16 + lk * 4 + r;
          int col = (wid * 2 + ct) * 16 + lr;
          Vb[row * NE + col] = __float2bfloat16(acc[st][ct][r]);
        }
  }
  // --- scores: wave handles 16 points from the LDS z tile ---
#pragma unroll 2
  for (int i = 0; i < 16; ++i) {
    int lp = wid * 16 + i;               // local point row
    size_t p = row0 + lp;
    int s = s_idx[lp];
    const short8v* g8 = (const short8v*)(G + (size_t)s * (8 * NE));
    short8v ga = g8[l];                  // head l>>4, d=(l&15)*8+j
    short8v gb = g8[64 + l];             // head 4+(l>>4)
    short8v zz = *(const short8v*)&zl[lp * 136 + (l & 15) * 8];
    float pa = 0.f, pb = 0.f;
#pragma unroll
    for (int j = 0; j < 8; ++j) {
      float zf = bfs(zz[j]);
      pa += zf * bfs(ga[j]);
      pb += zf * bfs(gb[j]);
    }
#pragma unroll
    for (int off = 1; off < 16; off <<= 1) {
      pa += __shfl_xor(pa, off);
      pb += __shfl_xor(pb, off);
    }
    if ((l & 15) == 0) {
      S[p * 8 + (l >> 4)] = pa * 0.25f;
      S[p * 8 + 4 + (l >> 4)] = pb * 0.25f;
    }
  }
}

// fused attention + Wo: 16 cells/block, 4 waves; Wo^T B-fragments read
// directly from global (L2-broadcast) -- no Wo LDS staging.
__global__ __launch_bounds__(256) void attn_wo_kernel(
    const __hip_bfloat16* __restrict__ Vb, const float* __restrict__ S,
    const float* __restrict__ FS, const float* __restrict__ fakeKV,
    const int* __restrict__ counts, const unsigned short* __restrict__ lists,
    const __hip_bfloat16* __restrict__ Wot, float* __restrict__ out) {
  __shared__ __hip_bfloat16 ob[16 * 136];   // O tile (bf16)
  __shared__ float sc[4][24][8];
  __shared__ unsigned short pl[4][24];
  int tid = threadIdx.x, w = tid >> 6, l = tid & 63;
  int cell0 = blockIdx.x * 16;
  for (int ci = 0; ci < 4; ++ci) {
    int row = w * 4 + ci;
    int cell = cell0 + row;
    int s = cell & (NS - 1);
    int cnt = min(counts[cell], CAP);
    if (l < cnt) {
      int pid = lists[cell * CAP + l];
      pl[w][l] = (unsigned short)pid;
      float4 a = *(const float4*)&S[(size_t)pid * 8];
      float4 b = *(const float4*)&S[(size_t)pid * 8 + 4];
      sc[w][l][0] = a.x; sc[w][l][1] = a.y; sc[w][l][2] = a.z; sc[w][l][3] = a.w;
      sc[w][l][4] = b.x; sc[w][l][5] = b.y; sc[w][l][6] = b.z; sc[w][l][7] = b.w;
    } else if (l == cnt) {
#pragma unroll
      for (int h = 0; h < 8; ++h) sc[w][l][h] = FS[(size_t)s * 8 + h];
    }
    __builtin_amdgcn_wave_barrier();
    if (l < 8) {
      int T = cnt + 1;
      float m = -1e30f;
      for (int t = 0; t < T; ++t) m = fmaxf(m, sc[w][t][l]);
      float sum = 0.f;
      for (int t = 0; t < T; ++t) {
        float e = __expf(sc[w][t][l] - m);
        sum += e;
        sc[w][t][l] = e;
      }
      float inv = 1.f / sum;
      for (int t = 0; t < T; ++t) sc[w][t][l] *= inv;
    }
    __builtin_amdgcn_wave_barrier();
    // PV: lane l covers d = 2l, 2l+1 (head l>>3)
    int h = l >> 3;
    float acc0 = 0.f, acc1 = 0.f;
    for (int t = 0; t < cnt; ++t) {
      unsigned vv = ((const unsigned*)(Vb + (size_t)pl[w][t] * NE))[l];
      float wt = sc[w][t][h];
      acc0 += wt * bfs((short)(vv & 0xffff));
      acc1 += wt * bfs((short)(vv >> 16));
    }
    float2 fv = *(const float2*)&fakeKV[NE + 2 * l];
    float wt = sc[w][cnt][h];
    acc0 += wt * fv.x;
    acc1 += wt * fv.y;
    *(unsigned*)&ob[row * 136 + 2 * l] = pk2(acc0, acc1);
  }
  __syncthreads();
  // Wo MFMA epilogue: wave w covers col tiles {2w, 2w+1}, all 16 rows
  int lr = l & 15, lk = l >> 4;
  const short* ol = (const short*)ob;
  const short* Wg = (const short*)Wot;
  short8v afr[4];
#pragma unroll
  for (int ks = 0; ks < 4; ++ks)
    afr[ks] = *(const short8v*)&ol[lr * 136 + ks * 32 + lk * 8];
  float4v acc[2] = {};
#pragma unroll
  for (int ct = 0; ct < 2; ++ct) {
    int col = (w * 2 + ct) * 16 + lr;
#pragma unroll
    for (int ks = 0; ks < 4; ++ks) {
      short8v bfr = *(const short8v*)&Wg[col * NE + ks * 32 + lk * 8];
      acc[ct] = __builtin_amdgcn_mfma_f32_16x16x32_bf16(afr[ks], bfr, acc[ct], 0, 0, 0);
    }
  }
  float* base = out + (size_t)OUT0 + (size_t)blockIdx.x * 16 * NE;
#pragma unroll
  for (int ct = 0; ct < 2; ++ct)
#pragma unroll
    for (int r = 0; r < 4; ++r) {
      int row = lk * 4 + r;
      int col = (w * 2 + ct) * 16 + lr;
      base[(size_t)row * NE + col] = acc[ct][r];
    }
}

extern "C" void kernel_launch(void* const* d_in, const int* in_sizes, int n_in,
                              void* d_out, int out_size, void* d_ws, size_t ws_size,
                              hipStream_t stream) {
  const float* xc_off  = (const float*)d_in[0];
  const float* xc_on   = (const float*)d_in[1];
  const float* zc_off  = (const float*)d_in[2];
  const float* latents = (const float*)d_in[4];
  const float* fake    = (const float*)d_in[5];
  const float* Wq      = (const float*)d_in[6];
  const float* Wk      = (const float*)d_in[7];
  const float* Wv      = (const float*)d_in[8];
  const float* Wo      = (const float*)d_in[9];
  float* out = (float*)d_out;

  char* ws = (char*)d_ws;
  int*            counts = (int*)(ws);
  unsigned short* lists  = (unsigned short*)(ws + 131072);
  float*          S      = (float*)(ws + 1441792);
  __hip_bfloat16* G      = (__hip_bfloat16*)(ws + 3538944);
  float*          FS     = (float*)(ws + 11927552);
  float*          fakeKV = (float*)(ws + 12058624);
  __hip_bfloat16* Wvt    = (__hip_bfloat16*)(ws + 12059648);
  __hip_bfloat16* Wot    = (__hip_bfloat16*)(ws + 12092416);
  __hip_bfloat16* Vb     = (__hip_bfloat16*)(ws + 12125184);

  hipLaunchKernelGGL(setup_prep_kernel, dim3(833), dim3(256), 0, stream,
                     xc_on, fake, latents, Wq, Wk, Wv, Wo,
                     out, counts, fakeKV, Wvt, Wot, G, FS);
  hipLaunchKernelGGL(vgemm_kernel, dim3(NPTS / 64), dim3(256), 0, stream,
                     zc_off, xc_off, xc_on, Wvt, G, counts, lists, Vb, S);
  hipLaunchKernelGGL(attn_wo_kernel, dim3(NCELL / 16), dim3(256), 0, stream,
                     Vb, S, FS, fakeKV, counts, lists, Wot, out);
}

// Round 10
// 69.695 us; speedup vs baseline: 1.2933x; 1.2075x over previous
//
#include <hip/hip_runtime.h>
#include <hip/hip_bf16.h>

#define NB 8
#define NU 8192
#define GN0 64
#define GN1 64
#define NS 4096
#define NE 128
#define NH 8
#define CAP 20
#define NPTS (NB * NU)               // 65536
#define NCELL (NB * NS)              // 32768
#define OUT0 (NB * GN0 * GN1 * 2)    // 65536 f32 passthrough

// ---------------------------------------------------------------------------
// ws layout (bytes), total ~37.2 MB (G/S/FS dropped; qf/Kb added):
//   counts @ 0        (131072)   int32 per cell (zeroed by setup blocks)
//   lists  @ 131072   (1310720)  u16 point ids per cell
//   qf     @ 1441792  (2097152)  f32 [NS][128] q = latents @ Wq
//   fakeKV @ 3538944  (1024)     f32 fakeK[128], fakeV[128]
//   Wt     @ 3539968  (65536)    bf16 [256][128]: rows 0..127 Wv^T, 128..255 Wk^T
//   Wot    @ 3605504  (32768)    bf16 Wo^T [col][k]
//   Vb     @ 3638272  (16777216) bf16 V = Z @ Wv
//   Kb     @ 20415488 (16777216) bf16 K = Z @ Wk
// ---------------------------------------------------------------------------

typedef __attribute__((ext_vector_type(8))) short short8v;
typedef __attribute__((ext_vector_type(4))) float float4v;

static __device__ inline unsigned pk2(float a, float b) {
  __hip_bfloat16 x = __float2bfloat16(a), y = __float2bfloat16(b);
  return ((unsigned)*(unsigned short*)&y << 16) | *(unsigned short*)&x;
}
static __device__ inline float bfs(short v) {
  unsigned u = (unsigned)(unsigned short)v << 16;
  return __builtin_bit_cast(float, u);
}

// block-range dispatch:
//   0..255   : out0 passthrough copy (+ counts zero)
//   256      : fakeKV row
//   257..320 : Wv^T / Wk^T -> Wt, Wo^T -> Wot (bf16)
//   321..832 : qf = latents @ Wq (8 rows/block, f32)
__global__ __launch_bounds__(256) void setup_kernel(
    const float* __restrict__ xc_on, const float* __restrict__ fake,
    const float* __restrict__ latents,
    const float* __restrict__ Wq, const float* __restrict__ Wk,
    const float* __restrict__ Wv, const float* __restrict__ Wo,
    float* __restrict__ out, int* __restrict__ counts,
    float* __restrict__ fakeKV, __hip_bfloat16* __restrict__ Wt,
    __hip_bfloat16* __restrict__ Wot, float* __restrict__ qf) {
  int t = threadIdx.x;
  int blk = blockIdx.x;
  if (blk < 256) {
    int i = blk * 256 + t;
    out[i] = xc_on[i];
    if (i < NCELL) counts[i] = 0;
    return;
  }
  if (blk == 256) {
    __shared__ float frow[NE];
    if (t < NE) frow[t] = fake[t];
    __syncthreads();
    int e = t & 127, half = t >> 7;
    const float* W = half ? Wv : Wk;
    float acc = 0.f;
    for (int j = 0; j < NE; ++j) acc += frow[j] * W[j * NE + e];
    fakeKV[half * NE + e] = acc;    // [0:128)=fakeK, [128:256)=fakeV
    return;
  }
  if (blk <= 320) {
    int flat = (blk - 257) * 256 + t;    // 0..16383 ; j=row, e=col
    int j = flat >> 7, e = flat & 127;
    Wt[e * NE + j] = __float2bfloat16(Wv[flat]);            // Wv^T rows 0..127
    Wt[(128 + e) * NE + j] = __float2bfloat16(Wk[flat]);    // Wk^T rows 128..255
    Wot[e * NE + j] = __float2bfloat16(Wo[flat]);
    return;
  }
  // ---- qf: 512 blocks, 8 latent rows each ----
  int s0 = (blk - 321) * 8;
  __shared__ float lrow[8][NE];
  for (int i = t; i < 8 * NE; i += 256)
    lrow[i >> 7][i & 127] = latents[(size_t)s0 * NE + i];
  __syncthreads();
  for (int i = t; i < 8 * NE; i += 256) {
    int sl = i >> 7, e = i & 127;
    float acc = 0.f;
    for (int j = 0; j < NE; ++j) acc += lrow[sl][j] * Wq[j * NE + e];
    qf[(size_t)(s0 + sl) * NE + e] = acc;
  }
}

// fused: nearest-cell assignment (lanes 0..63) + [V|K] = bf16(Z @ [Wv|Wk])
// via MFMA; B-fragments read directly from L2-hot Wt. 64 points/block.
__global__ __launch_bounds__(256) void vgemm_kernel(
    const float* __restrict__ z, const float* __restrict__ xc_off,
    const float* __restrict__ xc_on, const __hip_bfloat16* __restrict__ Wt,
    int* __restrict__ counts, unsigned short* __restrict__ lists,
    __hip_bfloat16* __restrict__ Vb, __hip_bfloat16* __restrict__ Kb) {
  __shared__ __hip_bfloat16 zb[64 * 136];
  int tid = threadIdx.x;
  size_t row0 = (size_t)blockIdx.x * 64;
  for (int n = 0; n < 8; ++n) {
    int flat = n * 1024 + tid * 4;       // 0..8191 f32
    int r = flat >> 7, c = flat & 127;
    float4 v = *(const float4*)&z[(row0 + r) * NE + c];
    uint2 u = {pk2(v.x, v.y), pk2(v.z, v.w)};
    *(uint2*)&zb[r * 136 + c] = u;
  }
  if (tid < 64) {                        // nearest: one lane per point
    int p = (int)row0 + tid;
    int b = p >> 13;
    const float* g = xc_on + (size_t)b * (GN0 * GN1 * 2);
    float c00 = g[0], c01 = g[GN1 * 2], c10 = g[1], c11 = g[3];
    float x0 = xc_off[(size_t)p * 2 + 0];
    float x1 = xc_off[(size_t)p * 2 + 1];
    float f0 = rintf((x0 - c00) / (c01 - c00));   // np.round = RNE
    float f1 = rintf((x1 - c10) / (c11 - c10));
    int i0 = (int)fminf(fmaxf(f0, 0.f), 63.f);
    int i1 = (int)fminf(fmaxf(f1, 0.f), 63.f);
    int cell = b * NS + i0 * GN1 + i1;
    int pos = atomicAdd(&counts[cell], 1);
    if (pos < CAP) lists[cell * CAP + pos] = (unsigned short)p;
  }
  __syncthreads();
  int wid = tid >> 6, l = tid & 63;
  int lr = l & 15, lk = l >> 4;
  const short* zl = (const short*)zb;
  const short* Wg = (const short*)Wt;
  float4v acc[4][4] = {};
  short8v bfrag[4][4];
#pragma unroll
  for (int ct = 0; ct < 4; ++ct) {
    int col = wid * 64 + ct * 16 + lr;   // 0..255 across the 4 waves
#pragma unroll
    for (int ks = 0; ks < 4; ++ks)
      bfrag[ct][ks] = *(const short8v*)&Wg[col * NE + ks * 32 + lk * 8];
  }
#pragma unroll
  for (int ks = 0; ks < 4; ++ks)
#pragma unroll
    for (int st = 0; st < 4; ++st) {
      short8v a = *(const short8v*)&zl[(st * 16 + lr) * 136 + ks * 32 + lk * 8];
#pragma unroll
      for (int ct = 0; ct < 4; ++ct)
        acc[st][ct] = __builtin_amdgcn_mfma_f32_16x16x32_bf16(a, bfrag[ct][ks], acc[st][ct], 0, 0, 0);
    }
  __hip_bfloat16* dst = (wid < 2) ? Vb : Kb;
  int cb = (wid & 1) * 64;               // col base within the 128-wide output
#pragma unroll
  for (int st = 0; st < 4; ++st)
#pragma unroll
    for (int ct = 0; ct < 4; ++ct)
#pragma unroll
      for (int r = 0; r < 4; ++r) {
        size_t row = row0 + st * 16 + lk * 4 + r;
        int col = cb + ct * 16 + lr;
        dst[row * NE + col] = __float2bfloat16(acc[st][ct][r]);
      }
}

// fused scores + softmax + PV + Wo: 16 cells/block, 4 waves (4 cells/wave).
// scores: q f32 (qf) . K bf16 gather, 8-lane-group reduce; Wo^T from global.
__global__ __launch_bounds__(256) void attn_wo_kernel(
    const __hip_bfloat16* __restrict__ Vb, const __hip_bfloat16* __restrict__ Kb,
    const float* __restrict__ qf, const float* __restrict__ fakeKV,
    const int* __restrict__ counts, const unsigned short* __restrict__ lists,
    const __hip_bfloat16* __restrict__ Wot, float* __restrict__ out) {
  __shared__ __hip_bfloat16 ob[16 * 136];   // O tile (bf16)
  __shared__ float sc[4][24][8];
  int tid = threadIdx.x, w = tid >> 6, l = tid & 63;
  int cell0 = blockIdx.x * 16;
  for (int ci = 0; ci < 4; ++ci) {
    int row = w * 4 + ci;
    int cell = cell0 + row;
    int s = cell & (NS - 1);
    int cnt = min(counts[cell], CAP);
    // lane l owns q[s][2l..2l+1] = head (l>>3), d = 2(l&7), 2(l&7)+1
    float2 qv = *(const float2*)&qf[(size_t)s * NE + 2 * l];
    int mypid = (l < cnt) ? (int)lists[cell * CAP + l] : 0;
    // scores per token: K dword gather + 2 FMA + 3 shfl (8-lane group)
    for (int t = 0; t < cnt; ++t) {
      int pid = __shfl(mypid, t);
      unsigned kd = ((const unsigned*)(Kb + (size_t)pid * NE))[l];
      float p = qv.x * bfs((short)(kd & 0xffff)) + qv.y * bfs((short)(kd >> 16));
      p += __shfl_xor(p, 1); p += __shfl_xor(p, 2); p += __shfl_xor(p, 4);
      if ((l & 7) == 0) sc[w][t][l >> 3] = p * 0.25f;
    }
    {
      float2 fk = *(const float2*)&fakeKV[2 * l];   // fakeK
      float p = qv.x * fk.x + qv.y * fk.y;
      p += __shfl_xor(p, 1); p += __shfl_xor(p, 2); p += __shfl_xor(p, 4);
      if ((l & 7) == 0) sc[w][cnt][l >> 3] = p * 0.25f;
    }
    __builtin_amdgcn_wave_barrier();
    if (l < 8) {
      int T = cnt + 1;
      float m = -1e30f;
      for (int t = 0; t < T; ++t) m = fmaxf(m, sc[w][t][l]);
      float sum = 0.f;
      for (int t = 0; t < T; ++t) {
        float e = __expf(sc[w][t][l] - m);
        sum += e;
        sc[w][t][l] = e;
      }
      float inv = 1.f / sum;
      for (int t = 0; t < T; ++t) sc[w][t][l] *= inv;
    }
    __builtin_amdgcn_wave_barrier();
    // PV: lane l covers d = 2l, 2l+1 (head l>>3)
    int h = l >> 3;
    float acc0 = 0.f, acc1 = 0.f;
    for (int t = 0; t < cnt; ++t) {
      int pid = __shfl(mypid, t);
      unsigned vv = ((const unsigned*)(Vb + (size_t)pid * NE))[l];
      float wt = sc[w][t][h];
      acc0 += wt * bfs((short)(vv & 0xffff));
      acc1 += wt * bfs((short)(vv >> 16));
    }
    float2 fv = *(const float2*)&fakeKV[NE + 2 * l];
    float wt = sc[w][cnt][h];
    acc0 += wt * fv.x;
    acc1 += wt * fv.y;
    *(unsigned*)&ob[row * 136 + 2 * l] = pk2(acc0, acc1);
  }
  __syncthreads();
  // Wo MFMA epilogue: wave w covers col tiles {2w, 2w+1}, all 16 rows
  int lr = l & 15, lk = l >> 4;
  const short* ol = (const short*)ob;
  const short* Wg = (const short*)Wot;
  short8v afr[4];
#pragma unroll
  for (int ks = 0; ks < 4; ++ks)
    afr[ks] = *(const short8v*)&ol[lr * 136 + ks * 32 + lk * 8];
  float4v acc[2] = {};
#pragma unroll
  for (int ct = 0; ct < 2; ++ct) {
    int col = (w * 2 + ct) * 16 + lr;
#pragma unroll
    for (int ks = 0; ks < 4; ++ks) {
      short8v bfr = *(const short8v*)&Wg[col * NE + ks * 32 + lk * 8];
      acc[ct] = __builtin_amdgcn_mfma_f32_16x16x32_bf16(afr[ks], bfr, acc[ct], 0, 0, 0);
    }
  }
  float* base = out + (size_t)OUT0 + (size_t)blockIdx.x * 16 * NE;
#pragma unroll
  for (int ct = 0; ct < 2; ++ct)
#pragma unroll
    for (int r = 0; r < 4; ++r) {
      int row = lk * 4 + r;
      int col = (w * 2 + ct) * 16 + lr;
      base[(size_t)row * NE + col] = acc[ct][r];
    }
}

extern "C" void kernel_launch(void* const* d_in, const int* in_sizes, int n_in,
                              void* d_out, int out_size, void* d_ws, size_t ws_size,
                              hipStream_t stream) {
  const float* xc_off  = (const float*)d_in[0];
  const float* xc_on   = (const float*)d_in[1];
  const float* zc_off  = (const float*)d_in[2];
  const float* latents = (const float*)d_in[4];
  const float* fake    = (const float*)d_in[5];
  const float* Wq      = (const float*)d_in[6];
  const float* Wk      = (const float*)d_in[7];
  const float* Wv      = (const float*)d_in[8];
  const float* Wo      = (const float*)d_in[9];
  float* out = (float*)d_out;

  char* ws = (char*)d_ws;
  int*            counts = (int*)(ws);
  unsigned short* lists  = (unsigned short*)(ws + 131072);
  float*          qf     = (float*)(ws + 1441792);
  float*          fakeKV = (float*)(ws + 3538944);
  __hip_bfloat16* Wt     = (__hip_bfloat16*)(ws + 3539968);
  __hip_bfloat16* Wot    = (__hip_bfloat16*)(ws + 3605504);
  __hip_bfloat16* Vb     = (__hip_bfloat16*)(ws + 3638272);
  __hip_bfloat16* Kb     = (__hip_bfloat16*)(ws + 20415488);

  hipLaunchKernelGGL(setup_kernel, dim3(833), dim3(256), 0, stream,
                     xc_on, fake, latents, Wq, Wk, Wv, Wo,
                     out, counts, fakeKV, Wt, Wot, qf);
  hipLaunchKernelGGL(vgemm_kernel, dim3(NPTS / 64), dim3(256), 0, stream,
                     zc_off, xc_off, xc_on, Wt, counts, lists, Vb, Kb);
  hipLaunchKernelGGL(attn_wo_kernel, dim3(NCELL / 16), dim3(256), 0, stream,
                     Vb, Kb, qf, fakeKV, counts, lists, Wot, out);
}

// Round 11
// 59.505 us; speedup vs baseline: 1.5147x; 1.1712x over previous
//
#include <hip/hip_runtime.h>
#include <hip/hip_bf16.h>

#define NB 8
#define NU 8192
#define GN0 64
#define GN1 64
#define NS 4096
#define NE 128
#define NH 8
#define CAP 20
#define NPTS (NB * NU)               // 65536
#define NCELL (NB * NS)              // 32768
#define OUT0 (NB * GN0 * GN1 * 2)    // 65536 f32 passthrough

// ---------------------------------------------------------------------------
// ws layout (bytes), total ~37.2 MB:
//   counts @ 0        (131072)   int32 per cell (zeroed by setup blocks)
//   lists  @ 131072   (1310720)  u16 point ids per cell
//   qf     @ 1441792  (2097152)  f32 [NS][128] q = latents @ Wq
//   fakeKV @ 3538944  (1024)     f32 fakeK[128], fakeV[128]
//   Wt     @ 3539968  (65536)    bf16 [256][128]: rows 0..127 Wv^T, 128..255 Wk^T
//   Wot    @ 3605504  (32768)    bf16 Wo^T [col][k]
//   Vb     @ 3638272  (16777216) bf16 V = Z @ Wv
//   Kb     @ 20415488 (16777216) bf16 K = Z @ Wk
//
// XCD pinning: vgemm block for batch b and attn block for batch b both land
// on XCD b (swizzle blk=(hw&7)*chunk+(hw>>3)), so batch b's V+K (4 MB) stays
// in that XCD's 4 MB L2 between producer and consumer.
// ---------------------------------------------------------------------------

typedef __attribute__((ext_vector_type(8))) short short8v;
typedef __attribute__((ext_vector_type(4))) float float4v;

static __device__ inline unsigned pk2(float a, float b) {
  __hip_bfloat16 x = __float2bfloat16(a), y = __float2bfloat16(b);
  return ((unsigned)*(unsigned short*)&y << 16) | *(unsigned short*)&x;
}
static __device__ inline float bfs(short v) {
  unsigned u = (unsigned)(unsigned short)v << 16;
  return __builtin_bit_cast(float, u);
}

// block-range dispatch:
//   0..255   : out0 passthrough copy (+ counts zero)
//   256      : fakeKV row
//   257..320 : Wv^T / Wk^T -> Wt, Wo^T -> Wot (bf16)
//   321..832 : qf = latents @ Wq (8 rows/block, f32)
__global__ __launch_bounds__(256) void setup_kernel(
    const float* __restrict__ xc_on, const float* __restrict__ fake,
    const float* __restrict__ latents,
    const float* __restrict__ Wq, const float* __restrict__ Wk,
    const float* __restrict__ Wv, const float* __restrict__ Wo,
    float* __restrict__ out, int* __restrict__ counts,
    float* __restrict__ fakeKV, __hip_bfloat16* __restrict__ Wt,
    __hip_bfloat16* __restrict__ Wot, float* __restrict__ qf) {
  int t = threadIdx.x;
  int blk = blockIdx.x;
  if (blk < 256) {
    int i = blk * 256 + t;
    out[i] = xc_on[i];
    if (i < NCELL) counts[i] = 0;
    return;
  }
  if (blk == 256) {
    __shared__ float frow[NE];
    if (t < NE) frow[t] = fake[t];
    __syncthreads();
    int e = t & 127, half = t >> 7;
    const float* W = half ? Wv : Wk;
    float acc = 0.f;
    for (int j = 0; j < NE; ++j) acc += frow[j] * W[j * NE + e];
    fakeKV[half * NE + e] = acc;    // [0:128)=fakeK, [128:256)=fakeV
    return;
  }
  if (blk <= 320) {
    int flat = (blk - 257) * 256 + t;    // 0..16383 ; j=row, e=col
    int j = flat >> 7, e = flat & 127;
    Wt[e * NE + j] = __float2bfloat16(Wv[flat]);            // Wv^T rows 0..127
    Wt[(128 + e) * NE + j] = __float2bfloat16(Wk[flat]);    // Wk^T rows 128..255
    Wot[e * NE + j] = __float2bfloat16(Wo[flat]);
    return;
  }
  // ---- qf: 512 blocks, 8 latent rows each ----
  int s0 = (blk - 321) * 8;
  __shared__ float lrow[8][NE];
  for (int i = t; i < 8 * NE; i += 256)
    lrow[i >> 7][i & 127] = latents[(size_t)s0 * NE + i];
  __syncthreads();
  for (int i = t; i < 8 * NE; i += 256) {
    int sl = i >> 7, e = i & 127;
    float acc = 0.f;
    for (int j = 0; j < NE; ++j) acc += lrow[sl][j] * Wq[j * NE + e];
    qf[(size_t)(s0 + sl) * NE + e] = acc;
  }
}

// fused: nearest-cell assignment (lanes 0..63) + [V|K] = bf16(Z @ [Wv|Wk])
// via MFMA; B-fragments read directly from L2-hot Wt. 64 points/block.
// Batch-pinned XCD swizzle: hw block n -> logical blk (n&7)*128 + (n>>3).
__global__ __launch_bounds__(256) void vgemm_kernel(
    const float* __restrict__ z, const float* __restrict__ xc_off,
    const float* __restrict__ xc_on, const __hip_bfloat16* __restrict__ Wt,
    int* __restrict__ counts, unsigned short* __restrict__ lists,
    __hip_bfloat16* __restrict__ Vb, __hip_bfloat16* __restrict__ Kb) {
  __shared__ __hip_bfloat16 zb[64 * 136];
  int tid = threadIdx.x;
  int blk = ((int)blockIdx.x & 7) * 128 + ((int)blockIdx.x >> 3);
  size_t row0 = (size_t)blk * 64;
  for (int n = 0; n < 8; ++n) {
    int flat = n * 1024 + tid * 4;       // 0..8191 f32
    int r = flat >> 7, c = flat & 127;
    float4 v = *(const float4*)&z[(row0 + r) * NE + c];
    uint2 u = {pk2(v.x, v.y), pk2(v.z, v.w)};
    *(uint2*)&zb[r * 136 + c] = u;
  }
  if (tid < 64) {                        // nearest: one lane per point
    int p = (int)row0 + tid;
    int b = p >> 13;
    const float* g = xc_on + (size_t)b * (GN0 * GN1 * 2);
    float c00 = g[0], c01 = g[GN1 * 2], c10 = g[1], c11 = g[3];
    float x0 = xc_off[(size_t)p * 2 + 0];
    float x1 = xc_off[(size_t)p * 2 + 1];
    float f0 = rintf((x0 - c00) / (c01 - c00));   // np.round = RNE
    float f1 = rintf((x1 - c10) / (c11 - c10));
    int i0 = (int)fminf(fmaxf(f0, 0.f), 63.f);
    int i1 = (int)fminf(fmaxf(f1, 0.f), 63.f);
    int cell = b * NS + i0 * GN1 + i1;
    int pos = atomicAdd(&counts[cell], 1);
    if (pos < CAP) lists[cell * CAP + pos] = (unsigned short)p;
  }
  __syncthreads();
  int wid = tid >> 6, l = tid & 63;
  int lr = l & 15, lk = l >> 4;
  const short* zl = (const short*)zb;
  const short* Wg = (const short*)Wt;
  float4v acc[4][4] = {};
  short8v bfrag[4][4];
#pragma unroll
  for (int ct = 0; ct < 4; ++ct) {
    int col = wid * 64 + ct * 16 + lr;   // 0..255 across the 4 waves
#pragma unroll
    for (int ks = 0; ks < 4; ++ks)
      bfrag[ct][ks] = *(const short8v*)&Wg[col * NE + ks * 32 + lk * 8];
  }
#pragma unroll
  for (int ks = 0; ks < 4; ++ks)
#pragma unroll
    for (int st = 0; st < 4; ++st) {
      short8v a = *(const short8v*)&zl[(st * 16 + lr) * 136 + ks * 32 + lk * 8];
#pragma unroll
      for (int ct = 0; ct < 4; ++ct)
        acc[st][ct] = __builtin_amdgcn_mfma_f32_16x16x32_bf16(a, bfrag[ct][ks], acc[st][ct], 0, 0, 0);
    }
  __hip_bfloat16* dst = (wid < 2) ? Vb : Kb;
  int cb = (wid & 1) * 64;               // col base within the 128-wide output
#pragma unroll
  for (int st = 0; st < 4; ++st)
#pragma unroll
    for (int ct = 0; ct < 4; ++ct)
#pragma unroll
      for (int r = 0; r < 4; ++r) {
        size_t row = row0 + st * 16 + lk * 4 + r;
        int col = cb + ct * 16 + lr;
        dst[row * NE + col] = __float2bfloat16(acc[st][ct][r]);
      }
}

// fused scores + softmax + PV + Wo: 16 cells/block, 4 waves, ONE CELL PER
// 16-LANE GROUP (4 cells in parallel per wave). Lane i of a group owns dims
// 8i..8i+7: K/V gathers are one 16B short8v load per lane; score reduce is
// a single shfl_xor(1). Batch-pinned XCD swizzle matches vgemm.
__global__ __launch_bounds__(256) void attn_wo_kernel(
    const __hip_bfloat16* __restrict__ Vb, const __hip_bfloat16* __restrict__ Kb,
    const float* __restrict__ qf, const float* __restrict__ fakeKV,
    const int* __restrict__ counts, const unsigned short* __restrict__ lists,
    const __hip_bfloat16* __restrict__ Wot, float* __restrict__ out) {
  __shared__ __hip_bfloat16 ob[16 * 136];   // O tile (bf16)
  __shared__ float sc[4][4][24][8];         // [wave][group][token][head]
  __shared__ unsigned short pl[4][4][24];
  int tid = threadIdx.x, w = tid >> 6, l = tid & 63;
  int g = l >> 4, i = l & 15;
  int blk = ((int)blockIdx.x & 7) * 256 + ((int)blockIdx.x >> 3);
  int row = w * 4 + g;
  int cell = blk * 16 + row;
  int s = cell & (NS - 1);
  int cnt = min(counts[cell], CAP);
  for (int t = i; t < cnt; t += 16)
    pl[w][g][t] = lists[cell * CAP + t];
  int d0 = i * 8;
  float4 qa = *(const float4*)&qf[(size_t)s * NE + d0];
  float4 qb = *(const float4*)&qf[(size_t)s * NE + d0 + 4];
  __builtin_amdgcn_wave_barrier();
  // scores: head h = i>>1 spans lanes {2h, 2h+1}
  for (int t = 0; t < cnt; ++t) {
    int pid = pl[w][g][t];
    short8v kv = *(const short8v*)(const short*)(Kb + (size_t)pid * NE + d0);
    float p = qa.x * bfs(kv[0]) + qa.y * bfs(kv[1]) + qa.z * bfs(kv[2]) + qa.w * bfs(kv[3])
            + qb.x * bfs(kv[4]) + qb.y * bfs(kv[5]) + qb.z * bfs(kv[6]) + qb.w * bfs(kv[7]);
    p += __shfl_xor(p, 1);
    if ((i & 1) == 0) sc[w][g][t][i >> 1] = p * 0.25f;
  }
  {
    float4 fa = *(const float4*)&fakeKV[d0];
    float4 fb = *(const float4*)&fakeKV[d0 + 4];
    float p = qa.x * fa.x + qa.y * fa.y + qa.z * fa.z + qa.w * fa.w
            + qb.x * fb.x + qb.y * fb.y + qb.z * fb.z + qb.w * fb.w;
    p += __shfl_xor(p, 1);
    if ((i & 1) == 0) sc[w][g][cnt][i >> 1] = p * 0.25f;
  }
  __builtin_amdgcn_wave_barrier();
  if (i < 8) {                        // lane i handles head i of its group
    int T = cnt + 1;
    float m = -1e30f;
    for (int t = 0; t < T; ++t) m = fmaxf(m, sc[w][g][t][i]);
    float sum = 0.f;
    for (int t = 0; t < T; ++t) {
      float e = __expf(sc[w][g][t][i] - m);
      sum += e;
      sc[w][g][t][i] = e;
    }
    float inv = 1.f / sum;
    for (int t = 0; t < T; ++t) sc[w][g][t][i] *= inv;
  }
  __builtin_amdgcn_wave_barrier();
  // PV: lane accumulates its 8 dims
  int h = i >> 1;
  float va[8] = {0.f, 0.f, 0.f, 0.f, 0.f, 0.f, 0.f, 0.f};
  for (int t = 0; t < cnt; ++t) {
    int pid = pl[w][g][t];
    short8v vv = *(const short8v*)(const short*)(Vb + (size_t)pid * NE + d0);
    float wt = sc[w][g][t][h];
#pragma unroll
    for (int j = 0; j < 8; ++j) va[j] += wt * bfs(vv[j]);
  }
  {
    float4 fa = *(const float4*)&fakeKV[NE + d0];
    float4 fb = *(const float4*)&fakeKV[NE + d0 + 4];
    float wt = sc[w][g][cnt][h];
    va[0] += wt * fa.x; va[1] += wt * fa.y; va[2] += wt * fa.z; va[3] += wt * fa.w;
    va[4] += wt * fb.x; va[5] += wt * fb.y; va[6] += wt * fb.z; va[7] += wt * fb.w;
  }
  {
    uint4 u = {pk2(va[0], va[1]), pk2(va[2], va[3]),
               pk2(va[4], va[5]), pk2(va[6], va[7])};
    *(uint4*)&ob[row * 136 + d0] = u;   // byte offset row*272 + i*16, 16B aligned
  }
  __syncthreads();
  // Wo MFMA epilogue: wave w covers col tiles {2w, 2w+1}, all 16 rows
  int lr = l & 15, lk = l >> 4;
  const short* ol = (const short*)ob;
  const short* Wg = (const short*)Wot;
  short8v afr[4];
#pragma unroll
  for (int ks = 0; ks < 4; ++ks)
    afr[ks] = *(const short8v*)&ol[lr * 136 + ks * 32 + lk * 8];
  float4v acc[2] = {};
#pragma unroll
  for (int ct = 0; ct < 2; ++ct) {
    int col = (w * 2 + ct) * 16 + lr;
#pragma unroll
    for (int ks = 0; ks < 4; ++ks) {
      short8v bfr = *(const short8v*)&Wg[col * NE + ks * 32 + lk * 8];
      acc[ct] = __builtin_amdgcn_mfma_f32_16x16x32_bf16(afr[ks], bfr, acc[ct], 0, 0, 0);
    }
  }
  float* base = out + (size_t)OUT0 + (size_t)blk * 16 * NE;
#pragma unroll
  for (int ct = 0; ct < 2; ++ct)
#pragma unroll
    for (int r = 0; r < 4; ++r) {
      int orow = lk * 4 + r;
      int col = (w * 2 + ct) * 16 + lr;
      base[(size_t)orow * NE + col] = acc[ct][r];
    }
}

extern "C" void kernel_launch(void* const* d_in, const int* in_sizes, int n_in,
                              void* d_out, int out_size, void* d_ws, size_t ws_size,
                              hipStream_t stream) {
  const float* xc_off  = (const float*)d_in[0];
  const float* xc_on   = (const float*)d_in[1];
  const float* zc_off  = (const float*)d_in[2];
  const float* latents = (const float*)d_in[4];
  const float* fake    = (const float*)d_in[5];
  const float* Wq      = (const float*)d_in[6];
  const float* Wk      = (const float*)d_in[7];
  const float* Wv      = (const float*)d_in[8];
  const float* Wo      = (const float*)d_in[9];
  float* out = (float*)d_out;

  char* ws = (char*)d_ws;
  int*            counts = (int*)(ws);
  unsigned short* lists  = (unsigned short*)(ws + 131072);
  float*          qf     = (float*)(ws + 1441792);
  float*          fakeKV = (float*)(ws + 3538944);
  __hip_bfloat16* Wt     = (__hip_bfloat16*)(ws + 3539968);
  __hip_bfloat16* Wot    = (__hip_bfloat16*)(ws + 3605504);
  __hip_bfloat16* Vb     = (__hip_bfloat16*)(ws + 3638272);
  __hip_bfloat16* Kb     = (__hip_bfloat16*)(ws + 20415488);

  hipLaunchKernelGGL(setup_kernel, dim3(833), dim3(256), 0, stream,
                     xc_on, fake, latents, Wq, Wk, Wv, Wo,
                     out, counts, fakeKV, Wt, Wot, qf);
  hipLaunchKernelGGL(vgemm_kernel, dim3(NPTS / 64), dim3(256), 0, stream,
                     zc_off, xc_off, xc_on, Wt, counts, lists, Vb, Kb);
  hipLaunchKernelGGL(attn_wo_kernel, dim3(NCELL / 16), dim3(256), 0, stream,
                     Vb, Kb, qf, fakeKV, counts, lists, Wot, out);
}